// Round 1
// baseline (35.301 us; speedup 1.0000x reference)
//
#include <hip/hip_runtime.h>

// RefinementCAM: B=4, C=256, H=W=64, N=4096.
// Factorized: out[b,n] = fn[:,n] . (sum_m fn[:,m]*cam[m])  -- no NxN sim needed.

constexpr int B  = 4;
constexpr int C  = 256;
constexpr int N  = 4096;        // H*W
constexpr int BN = B * N;       // 16384

__device__ __forceinline__ float waveReduceSum(float v) {
#pragma unroll
    for (int o = 32; o > 0; o >>= 1) v += __shfl_down(v, o, 64);
    return v;
}
__device__ __forceinline__ float waveReduceMin(float v) {
#pragma unroll
    for (int o = 32; o > 0; o >>= 1) v = fminf(v, __shfl_down(v, o, 64));
    return v;
}
__device__ __forceinline__ float waveReduceMax(float v) {
#pragma unroll
    for (int o = 32; o > 0; o >>= 1) v = fmaxf(v, __shfl_down(v, o, 64));
    return v;
}

// K1: per pixel p=(b,n): mask m, channel sum of (feat*m)^2, scale s=m/denom, w=s*cam.
__global__ void k_scale(const float* __restrict__ cam, const float* __restrict__ feat,
                        float* __restrict__ s, float* __restrict__ w) {
    int p = blockIdx.x * blockDim.x + threadIdx.x;   // 64 blocks * 256 = 16384
    int b = p >> 12;
    int n = p & (N - 1);
    float cv = cam[p];
    float m = ((cv >= 0.3f ? 1.f : 0.f) + (cv >= 0.4f ? 1.f : 0.f) +
               (cv >= 0.5f ? 1.f : 0.f)) / 3.f;
    const float* fp = feat + (size_t)b * (C * N) + n;
    float ss = 0.f;
#pragma unroll 8
    for (int c = 0; c < C; ++c) {
        float x = fp[(size_t)c * N] * m;            // lanes contiguous in n -> coalesced
        ss = fmaf(x, x, ss);
    }
    float denom = fmaxf(sqrtf(ss), 1e-12f);
    float sc = m / denom;
    s[p] = sc;
    w[p] = sc * cv;
}

// K2: v[b,c] = sum_n feat[b,c,n] * w[b,n].  One block per (b,c).
__global__ void k_v(const float* __restrict__ feat, const float* __restrict__ w,
                    float* __restrict__ v) {
    int bc = blockIdx.x;                 // 1024
    int b = bc >> 8, c = bc & (C - 1);
    const float* fp = feat + (size_t)b * (C * N) + (size_t)c * N;
    const float* wp = w + b * N;
    float acc = 0.f;
    int t = threadIdx.x;
#pragma unroll
    for (int i = 0; i < 4; ++i) {
        int idx = (i * 256 + t) * 4;
        float4 x  = *(const float4*)(fp + idx);
        float4 ww = *(const float4*)(wp + idx);
        acc = fmaf(x.x, ww.x, acc);
        acc = fmaf(x.y, ww.y, acc);
        acc = fmaf(x.z, ww.z, acc);
        acc = fmaf(x.w, ww.w, acc);
    }
    __shared__ float red[4];
    float tot = waveReduceSum(acc);
    if ((t & 63) == 0) red[t >> 6] = tot;
    __syncthreads();
    if (t == 0) v[bc] = red[0] + red[1] + red[2] + red[3];
}

// K3: out[b,n] = s[b,n] * sum_c feat[b,c,n] * v[b,c].
__global__ void k_out(const float* __restrict__ feat, const float* __restrict__ s,
                      const float* __restrict__ v, float* __restrict__ ob) {
    __shared__ float vs[C];
    int p = blockIdx.x * blockDim.x + threadIdx.x;   // 64 blocks * 256
    int b = p >> 12;
    int n = p & (N - 1);
    vs[threadIdx.x] = v[b * C + threadIdx.x];        // b uniform per block (1024 px/blk)
    __syncthreads();
    const float* fp = feat + (size_t)b * (C * N) + n;
    float acc = 0.f;
#pragma unroll 8
    for (int c = 0; c < C; ++c)
        acc = fmaf(fp[(size_t)c * N], vs[c], acc);   // vs[c] broadcast: conflict-free
    ob[p] = s[p] * acc;
}

// K4: per-batch min/max of out.
__global__ void k_minmax(const float* __restrict__ ob, float* __restrict__ mnmx) {
    int b = blockIdx.x;
    const float* op = ob + b * N;
    float mn = 3.0e38f, mx = -3.0e38f;
    for (int i = threadIdx.x; i < N; i += 256) {
        float x = op[i];
        mn = fminf(mn, x);
        mx = fmaxf(mx, x);
    }
    __shared__ float rmn[4], rmx[4];
    mn = waveReduceMin(mn);
    mx = waveReduceMax(mx);
    int t = threadIdx.x;
    if ((t & 63) == 0) { rmn[t >> 6] = mn; rmx[t >> 6] = mx; }
    __syncthreads();
    if (t == 0) {
        mnmx[b]     = fminf(fminf(rmn[0], rmn[1]), fminf(rmn[2], rmn[3]));
        mnmx[B + b] = fmaxf(fmaxf(rmx[0], rmx[1]), fmaxf(rmx[2], rmx[3]));
    }
}

// K5: ref = (out-mn)/(mx+1e-5-mn); write d_out; per-block partial sum of |ref-cam|.
__global__ void k_rescale(const float* __restrict__ ob, const float* __restrict__ cam,
                          const float* __restrict__ mnmx, float* __restrict__ out,
                          float* __restrict__ partial) {
    int p = blockIdx.x * blockDim.x + threadIdx.x;   // 64 blocks * 256
    int b = p >> 12;
    float mn = mnmx[b];
    float mx = mnmx[B + b] + 1e-5f;
    float r = (ob[p] - mn) / (mx - mn);
    out[p] = r;
    float ad = fabsf(r - cam[p]);
    __shared__ float red[4];
    float tot = waveReduceSum(ad);
    int t = threadIdx.x;
    if ((t & 63) == 0) red[t >> 6] = tot;
    __syncthreads();
    if (t == 0) partial[blockIdx.x] = red[0] + red[1] + red[2] + red[3];
}

// K6: loss = sum(partial)/BN -> d_out[BN].
__global__ void k_loss(const float* __restrict__ partial, float* __restrict__ out) {
    float v = partial[threadIdx.x];                  // 64 threads
    v = waveReduceSum(v);
    if (threadIdx.x == 0) out[BN] = v / (float)BN;
}

extern "C" void kernel_launch(void* const* d_in, const int* in_sizes, int n_in,
                              void* d_out, int out_size, void* d_ws, size_t ws_size,
                              hipStream_t stream) {
    const float* cam  = (const float*)d_in[0];   // (4,64,64)
    const float* feat = (const float*)d_in[1];   // (4,256,64,64)
    float* out = (float*)d_out;                  // [16384 ref][1 loss]
    float* ws  = (float*)d_ws;

    float* w    = ws;            // 16384
    float* s    = ws + 16384;    // 16384
    float* v    = ws + 32768;    // 1024
    float* ob   = ws + 33792;    // 16384
    float* mnmx = ws + 50176;    // 8
    float* part = ws + 50184;    // 64

    k_scale  <<<BN / 256, 256, 0, stream>>>(cam, feat, s, w);
    k_v      <<<B * C,    256, 0, stream>>>(feat, w, v);
    k_out    <<<BN / 256, 256, 0, stream>>>(feat, s, v, ob);
    k_minmax <<<B,        256, 0, stream>>>(ob, mnmx);
    k_rescale<<<BN / 256, 256, 0, stream>>>(ob, cam, mnmx, out, part);
    k_loss   <<<1,         64, 0, stream>>>(part, out);
}